// Round 2
// baseline (366.843 us; speedup 1.0000x reference)
//
#include <hip/hip_runtime.h>
#include <math.h>

#define IN_DIM 512
#define EMBED 128
#define OUT_DIM 64
#define NBPAD 256      // padded bucket count (actual NB = ceil(N/256) = 196)
#define SEGSH 12       // 4096 edges per bin block
#define CAP_LDS 10240  // build LDS capacity (mean 8430, +19 sigma)

typedef __attribute__((ext_vector_type(8))) short bf16x8;
typedef __attribute__((ext_vector_type(4))) float f32x4;

__device__ __forceinline__ float lrelu(float v, float s) { return v > 0.f ? v : v * s; }

__device__ __forceinline__ float readlane_f(float v, int l) {
  return __int_as_float(__builtin_amdgcn_readlane(__float_as_int(v), l));
}

__device__ __forceinline__ unsigned short f2bf(float f) {
  unsigned int u = __float_as_uint(f);
  u += 0x7fff + ((u >> 16) & 1);  // RTNE
  return (unsigned short)(u >> 16);
}
__device__ __forceinline__ float bf2f(unsigned short h) {
  return __uint_as_float(((unsigned int)h) << 16);
}

// packed f32x2 -> bf16x2 (low half = src0, high half = src1)
__device__ __forceinline__ unsigned int cvt_pk_bf16(float a, float b) {
  unsigned int r;
  asm("v_cvt_pk_bf16_f32 %0, %1, %2" : "=v"(r) : "v"(a), "v"(b));
  return r;
}

#define LDA 40  // bf16 LDS stride for gemm2 (16B-aligned rows)

// ---------------------------------------------------------------------------
// Prep: split W (fp32) into bf16 hi/lo planes once. 65536 elems -> ~2 us.
// ---------------------------------------------------------------------------
__global__ __launch_bounds__(256) void split_w_kernel(
    const float* __restrict__ W, unsigned short* __restrict__ Wh,
    unsigned short* __restrict__ Wl, int total) {
  int i = (blockIdx.x * 256 + threadIdx.x) * 4;
  if (i >= total) return;
  float4 v = *(const float4*)(W + i);
  unsigned int h0 = cvt_pk_bf16(v.x, v.y);
  unsigned int h1 = cvt_pk_bf16(v.z, v.w);
  float r0 = v.x - __uint_as_float(h0 << 16);
  float r1 = v.y - __uint_as_float(h0 & 0xffff0000u);
  float r2 = v.z - __uint_as_float(h1 << 16);
  float r3 = v.w - __uint_as_float(h1 & 0xffff0000u);
  unsigned int l0 = cvt_pk_bf16(r0, r1);
  unsigned int l1 = cvt_pk_bf16(r2, r3);
  uint2 hh = make_uint2(h0, h1);
  uint2 ll = make_uint2(l0, l1);
  *(uint2*)(Wh + i) = hh;
  *(uint2*)(Wl + i) = ll;
}

// ---------------------------------------------------------------------------
// K1 (MFMA split-bf16): h = leaky_relu(x @ Wd^T + bd, 0.01)
// v3: barrier-free K-loop. Full B panel (64x512 hi+lo = 128KB) resident in
// LDS (staged once, XOR-swizzled). A streamed global->reg per wave, 16 fully
// unrolled k-steps with no __syncthreads -> deep load pipelining via ILP.
// ---------------------------------------------------------------------------
__global__ __launch_bounds__(512) void gemm1_mfma_kernel(
    const float* __restrict__ x, const unsigned short* __restrict__ Wdh,
    const unsigned short* __restrict__ Wdl, const float* __restrict__ bd,
    float* __restrict__ h, int N) {
  __shared__ __align__(16) unsigned char Bsm[131072];  // [0,64K) hi, [64K,128K) lo

  const int tid = threadIdx.x;
  const int lane = tid & 63;
  const int wid = tid >> 6;   // 0..7
  const int wr = wid >> 1;    // 0..3 : 32-row m slice
  const int wc = wid & 1;     // 0..1 : 32-col n slice
  const int mblk = blockIdx.x * 128;
  const int nblk = blockIdx.y * 64;
  const int quad = lane >> 4;
  const int l15 = lane & 15;

  // ---- A fragment pointers (issue first loads before staging barrier) ----
  int r0g = mblk + wr * 32 + l15;        // mi=0 row
  int r1g = r0g + 16;                    // mi=1 row
  int r0c = r0g < N ? r0g : N - 1;       // clamp (masked at store)
  int r1c = r1g < N ? r1g : N - 1;
  const float* ap0 = x + (size_t)r0c * IN_DIM + quad * 8;
  const float* ap1 = x + (size_t)r1c * IN_DIM + quad * 8;

  float4 t0a, t0b, t1a, t1b;
  auto load_step = [&](int k0) {
    t0a = *(const float4*)(ap0 + k0);
    t0b = *(const float4*)(ap0 + k0 + 4);
    t1a = *(const float4*)(ap1 + k0);
    t1b = *(const float4*)(ap1 + k0 + 4);
  };
  load_step(0);

  // ---- stage B panel (64 rows x 512 k, hi+lo) into LDS, swizzled ----
  {
    const int o = tid * 128;   // byte offset within 64KB plane; 512*128 = 64KB
    const int row = o >> 10;   // 0..63
    const int colb = o & 1023;
    const unsigned short* srch = Wdh + (size_t)(nblk + row) * IN_DIM;
    const unsigned short* srcl = Wdl + (size_t)(nblk + row) * IN_DIM;
    const int sw = (row & 7) << 4;
#pragma unroll
    for (int c = 0; c < 8; ++c) {
      int byte = colb + c * 16;
      uint4 vh = *(const uint4*)((const char*)srch + byte);
      uint4 vl = *(const uint4*)((const char*)srcl + byte);
      int dst = (row << 10) | (byte ^ sw);
      *(uint4*)(Bsm + dst) = vh;
      *(uint4*)(Bsm + 65536 + dst) = vl;
    }
  }

  f32x4 acc[2][2];
#pragma unroll
  for (int i = 0; i < 2; ++i)
#pragma unroll
    for (int j = 0; j < 2; ++j) acc[i][j] = (f32x4){0.f, 0.f, 0.f, 0.f};

  // B LDS read bases: rows brow0 (ni=0) and brow0+16 (ni=1) share (row&7)
  const int brow0 = wc * 32 + l15;
  const int sw = (brow0 & 7) << 4;                 // bits 4..6
  const int qx = (quad << 4) ^ (sw & 48);          // bits 4..5 component
  const int s6 = sw & 64;                          // bit 6 component
  const unsigned char* pH = Bsm + (brow0 << 10);
  const unsigned char* pL = pH + 65536;

  __syncthreads();  // B resident; K-loop below has NO barriers

#pragma unroll
  for (int s = 0; s < IN_DIM / 32; ++s) {
    const int k0 = s * 32;
    // convert current A regs -> split-bf16 fragments
    float a0[8] = {t0a.x, t0a.y, t0a.z, t0a.w, t0b.x, t0b.y, t0b.z, t0b.w};
    float a1[8] = {t1a.x, t1a.y, t1a.z, t1a.w, t1b.x, t1b.y, t1b.z, t1b.w};
    union { unsigned int u[4]; bf16x8 v; } H0, L0, H1, L1;
#pragma unroll
    for (int i = 0; i < 4; ++i) {
      unsigned int hp0 = cvt_pk_bf16(a0[2 * i], a0[2 * i + 1]);
      float q0 = a0[2 * i] - __uint_as_float(hp0 << 16);
      float q1 = a0[2 * i + 1] - __uint_as_float(hp0 & 0xffff0000u);
      H0.u[i] = hp0;
      L0.u[i] = cvt_pk_bf16(q0, q1);
      unsigned int hp1 = cvt_pk_bf16(a1[2 * i], a1[2 * i + 1]);
      float q2 = a1[2 * i] - __uint_as_float(hp1 << 16);
      float q3 = a1[2 * i + 1] - __uint_as_float(hp1 & 0xffff0000u);
      H1.u[i] = hp1;
      L1.u[i] = cvt_pk_bf16(q2, q3);
    }

    if (s + 1 < IN_DIM / 32) load_step(k0 + 32);  // next step's loads in flight

    // B fragments from resident LDS (swizzled address, 2-way max conflict)
    const int vb = ((k0 << 1) ^ s6) | qx;
    bf16x8 bh0 = *(const bf16x8*)(pH + vb);
    bf16x8 bh1 = *(const bf16x8*)(pH + vb + (16 << 10));
    bf16x8 bl0 = *(const bf16x8*)(pL + vb);
    bf16x8 bl1 = *(const bf16x8*)(pL + vb + (16 << 10));

    acc[0][0] = __builtin_amdgcn_mfma_f32_16x16x32_bf16(H0.v, bh0, acc[0][0], 0, 0, 0);
    acc[0][0] = __builtin_amdgcn_mfma_f32_16x16x32_bf16(L0.v, bh0, acc[0][0], 0, 0, 0);
    acc[0][0] = __builtin_amdgcn_mfma_f32_16x16x32_bf16(H0.v, bl0, acc[0][0], 0, 0, 0);
    acc[0][1] = __builtin_amdgcn_mfma_f32_16x16x32_bf16(H0.v, bh1, acc[0][1], 0, 0, 0);
    acc[0][1] = __builtin_amdgcn_mfma_f32_16x16x32_bf16(L0.v, bh1, acc[0][1], 0, 0, 0);
    acc[0][1] = __builtin_amdgcn_mfma_f32_16x16x32_bf16(H0.v, bl1, acc[0][1], 0, 0, 0);
    acc[1][0] = __builtin_amdgcn_mfma_f32_16x16x32_bf16(H1.v, bh0, acc[1][0], 0, 0, 0);
    acc[1][0] = __builtin_amdgcn_mfma_f32_16x16x32_bf16(L1.v, bh0, acc[1][0], 0, 0, 0);
    acc[1][0] = __builtin_amdgcn_mfma_f32_16x16x32_bf16(H1.v, bl0, acc[1][0], 0, 0, 0);
    acc[1][1] = __builtin_amdgcn_mfma_f32_16x16x32_bf16(H1.v, bh1, acc[1][1], 0, 0, 0);
    acc[1][1] = __builtin_amdgcn_mfma_f32_16x16x32_bf16(L1.v, bh1, acc[1][1], 0, 0, 0);
    acc[1][1] = __builtin_amdgcn_mfma_f32_16x16x32_bf16(H1.v, bl1, acc[1][1], 0, 0, 0);
  }

#pragma unroll
  for (int mi = 0; mi < 2; ++mi)
#pragma unroll
    for (int ni = 0; ni < 2; ++ni) {
      int n = nblk + wc * 32 + ni * 16 + l15;
      float b = bd[n];
#pragma unroll
      for (int r = 0; r < 4; ++r) {
        int m = mblk + wr * 32 + mi * 16 + quad * 4 + r;
        if (m < N) h[(size_t)m * EMBED + n] = lrelu(acc[mi][ni][r] + b, 0.01f);
      }
    }
}

// ---------------------------------------------------------------------------
// K2 (MFMA split-bf16): g = h @ Wg^T, fused att-dot epilogue.
// (unchanged this round)
// ---------------------------------------------------------------------------
__global__ __launch_bounds__(256) void gemm2_mfma_kernel(
    const float* __restrict__ h, const float* __restrict__ Wg,
    const float* __restrict__ att_src, const float* __restrict__ att_dst,
    float* __restrict__ g, float* __restrict__ a_src, float* __restrict__ a_dst,
    int N) {
  __shared__ __align__(16) unsigned short Ah[128][LDA];
  __shared__ __align__(16) unsigned short Al[128][LDA];
  __shared__ __align__(16) unsigned short Bh[64][LDA];
  __shared__ __align__(16) unsigned short Bl[64][LDA];

  const int tid = threadIdx.x;
  const int lane = tid & 63;
  const int wid = tid >> 6;
  const int wr = wid >> 1, wc = wid & 1;
  const int mblk = blockIdx.x * 128;
  const int quad = lane >> 4;
  const int l15 = lane & 15;

  const int arow = tid >> 1, acb = (tid & 1) * 16;
  const int brow = tid >> 2, bcb = (tid & 3) * 8;
  const bool avalid = (mblk + arow) < N;
  const float* aptr = h + (size_t)(mblk + arow) * EMBED + acb;
  const float* bptr = Wg + (size_t)brow * EMBED + bcb;

  f32x4 acc[4][2];
#pragma unroll
  for (int i = 0; i < 4; ++i)
#pragma unroll
    for (int j = 0; j < 2; ++j) acc[i][j] = (f32x4){0.f, 0.f, 0.f, 0.f};

  float4 t0, t1, t2, t3, u0, u1;
  auto do_load = [&](int k0) {
    if (avalid) {
      t0 = *(const float4*)(aptr + k0);
      t1 = *(const float4*)(aptr + k0 + 4);
      t2 = *(const float4*)(aptr + k0 + 8);
      t3 = *(const float4*)(aptr + k0 + 12);
    } else {
      t0 = t1 = t2 = t3 = make_float4(0.f, 0.f, 0.f, 0.f);
    }
    u0 = *(const float4*)(bptr + k0);
    u1 = *(const float4*)(bptr + k0 + 4);
  };
  do_load(0);

  for (int k0 = 0; k0 < EMBED; k0 += 32) {
    float av[16] = {t0.x, t0.y, t0.z, t0.w, t1.x, t1.y, t1.z, t1.w,
                    t2.x, t2.y, t2.z, t2.w, t3.x, t3.y, t3.z, t3.w};
    union { unsigned short us[16]; uint4 v[2]; } AH, AL;
#pragma unroll
    for (int i = 0; i < 16; ++i) {
      unsigned short hi = f2bf(av[i]);
      AH.us[i] = hi;
      AL.us[i] = f2bf(av[i] - bf2f(hi));
    }
    float bv[8] = {u0.x, u0.y, u0.z, u0.w, u1.x, u1.y, u1.z, u1.w};
    union { unsigned short us[8]; uint4 v; } BH, BL;
#pragma unroll
    for (int i = 0; i < 8; ++i) {
      unsigned short hi = f2bf(bv[i]);
      BH.us[i] = hi;
      BL.us[i] = f2bf(bv[i] - bf2f(hi));
    }

    __syncthreads();
    *(uint4*)&Ah[arow][acb] = AH.v[0];
    *(uint4*)&Ah[arow][acb + 8] = AH.v[1];
    *(uint4*)&Al[arow][acb] = AL.v[0];
    *(uint4*)&Al[arow][acb + 8] = AL.v[1];
    *(uint4*)&Bh[brow][bcb] = BH.v;
    *(uint4*)&Bl[brow][bcb] = BL.v;
    __syncthreads();

    if (k0 + 32 < EMBED) do_load(k0 + 32);

    bf16x8 ah[4], al[4], bh[2], bl[2];
#pragma unroll
    for (int mi = 0; mi < 4; ++mi) {
      int r = wr * 64 + mi * 16 + l15;
      ah[mi] = *(const bf16x8*)&Ah[r][quad * 8];
      al[mi] = *(const bf16x8*)&Al[r][quad * 8];
    }
#pragma unroll
    for (int ni = 0; ni < 2; ++ni) {
      int r = wc * 32 + ni * 16 + l15;
      bh[ni] = *(const bf16x8*)&Bh[r][quad * 8];
      bl[ni] = *(const bf16x8*)&Bl[r][quad * 8];
    }
#pragma unroll
    for (int mi = 0; mi < 4; ++mi)
#pragma unroll
      for (int ni = 0; ni < 2; ++ni) {
        acc[mi][ni] = __builtin_amdgcn_mfma_f32_16x16x32_bf16(ah[mi], bh[ni], acc[mi][ni], 0, 0, 0);
        acc[mi][ni] = __builtin_amdgcn_mfma_f32_16x16x32_bf16(al[mi], bh[ni], acc[mi][ni], 0, 0, 0);
        acc[mi][ni] = __builtin_amdgcn_mfma_f32_16x16x32_bf16(ah[mi], bl[ni], acc[mi][ni], 0, 0, 0);
      }
  }

  float as_[2], ad_[2];
#pragma unroll
  for (int ni = 0; ni < 2; ++ni) {
    int n = wc * 32 + ni * 16 + l15;
    as_[ni] = att_src[n];
    ad_[ni] = att_dst[n];
  }
#pragma unroll
  for (int mi = 0; mi < 4; ++mi) {
#pragma unroll
    for (int r = 0; r < 4; ++r) {
      int m = mblk + wr * 64 + mi * 16 + quad * 4 + r;
      float ps = acc[mi][0][r] * as_[0] + acc[mi][1][r] * as_[1];
      float pd = acc[mi][0][r] * ad_[0] + acc[mi][1][r] * ad_[1];
#pragma unroll
      for (int d = 1; d < 16; d <<= 1) {
        ps += __shfl_xor(ps, d, 64);
        pd += __shfl_xor(pd, d, 64);
      }
      if (m < N) {
#pragma unroll
        for (int ni = 0; ni < 2; ++ni) {
          int n = wc * 32 + ni * 16 + l15;
          g[(size_t)m * OUT_DIM + n] = acc[mi][ni][r];
        }
        if (l15 == 0 && wc == 0) {
          a_src[m] = ps;
          a_dst[m] = pd;
        }
      }
    }
  }
  __syncthreads();
#pragma unroll
  for (int mi = 0; mi < 4; ++mi) {
#pragma unroll
    for (int r = 0; r < 4; ++r) {
      int m = mblk + wr * 64 + mi * 16 + quad * 4 + r;
      float ps = acc[mi][0][r] * as_[0] + acc[mi][1][r] * as_[1];
      float pd = acc[mi][0][r] * ad_[0] + acc[mi][1][r] * ad_[1];
#pragma unroll
      for (int d = 1; d < 16; d <<= 1) {
        ps += __shfl_xor(ps, d, 64);
        pd += __shfl_xor(pd, d, 64);
      }
      if (m < N && l15 == 0 && wc == 1) {
        atomicAdd(&a_src[m], ps);
        atomicAdd(&a_dst[m], pd);
      }
    }
  }
}

// ---------------------------------------------------------------------------
// Edge phase (deterministic software write-combining bin, parallel alloc)
// ---------------------------------------------------------------------------
__global__ __launch_bounds__(256) void hist_count_kernel(
    const int* __restrict__ ei, int* __restrict__ histT, int nblkP, int E,
    int N) {
  __shared__ int cnt[NBPAD];
  const int t = threadIdx.x;
  cnt[t] = 0;
  __syncthreads();
  const int T = E + N;
  const int base = blockIdx.x << SEGSH;
#pragma unroll
  for (int q = 0; q < (1 << SEGSH) / 256; ++q) {
    int i = base + q * 256 + t;
    if (i < T) {
      int d = (i < E) ? ei[E + i] : (i - E);
      atomicAdd(&cnt[d >> 8], 1);
    }
  }
  __syncthreads();
  histT[(size_t)t * nblkP + blockIdx.x] = cnt[t];
}

__global__ __launch_bounds__(256) void row_scan_kernel(
    int* __restrict__ histT, int* __restrict__ bucket_tot, int nblkP) {
  __shared__ int sc[256];
  const int t = threadIdx.x;
  int* row = histT + (size_t)blockIdx.x * nblkP;
  const int per = (nblkP + 255) / 256;
  int loc[8];
  int sum = 0;
#pragma unroll 4
  for (int j = 0; j < per; ++j) {
    int idx = t * per + j;
    int v = (idx < nblkP) ? row[idx] : 0;
    loc[j] = sum;
    sum += v;
  }
  sc[t] = sum;
  __syncthreads();
  for (int dlt = 1; dlt < 256; dlt <<= 1) {
    int add = (t >= dlt) ? sc[t - dlt] : 0;
    __syncthreads();
    sc[t] += add;
    __syncthreads();
  }
  const int off = sc[t] - sum;
#pragma unroll 4
  for (int j = 0; j < per; ++j) {
    int idx = t * per + j;
    if (idx < nblkP) row[idx] = off + loc[j];
  }
  if (t == 255) bucket_tot[blockIdx.x] = sc[255];
}

__global__ __launch_bounds__(256) void base_scan_kernel(
    const int* __restrict__ bucket_tot, int* __restrict__ bucket_base,
    int* __restrict__ offsets, int N, int T) {
  __shared__ int sc[256];
  const int t = threadIdx.x;
  int v = bucket_tot[t];
  sc[t] = v;
  __syncthreads();
  for (int dlt = 1; dlt < 256; dlt <<= 1) {
    int add = (t >= dlt) ? sc[t - dlt] : 0;
    __syncthreads();
    sc[t] += add;
    __syncthreads();
  }
  bucket_base[t] = sc[t] - v;
  if (t == 0) offsets[N] = T;
}

__global__ __launch_bounds__(256) void bin_kernel(
    const int* __restrict__ ei, const int* __restrict__ histT,
    const int* __restrict__ bucket_base, int* __restrict__ stageB, int nblkP,
    int E, int N) {
  __shared__ int cnt[NBPAD];
  __shared__ int basev[NBPAD];
  const int t = threadIdx.x;
  cnt[t] = 0;
  basev[t] = bucket_base[t] + histT[(size_t)t * nblkP + blockIdx.x];
  __syncthreads();
  const int T = E + N;
  const int base = blockIdx.x << SEGSH;
#pragma unroll
  for (int q = 0; q < (1 << SEGSH) / 256; ++q) {
    int i = base + q * 256 + t;
    if (i < T) {
      int s, d;
      if (i < E) {
        s = ei[i];
        d = ei[E + i];
      } else {
        s = d = i - E;
      }
      int b = d >> 8;
      int r = atomicAdd(&cnt[b], 1);
      stageB[basev[b] + r] = (s << 8) | (d & 255);
    }
  }
}

__global__ __launch_bounds__(256) void build_kernel(
    const int* __restrict__ stageB, const int* __restrict__ bucket_base,
    const int* __restrict__ bucket_tot, const float* __restrict__ a_src,
    const float* __restrict__ a_dst, int* __restrict__ offsets,
    int2* __restrict__ csr_pack, int N) {
  __shared__ int cnt[256];
  __shared__ int pre[256];
  __shared__ int cur[256];
  __shared__ int2 buf[CAP_LDS];
  const int b = blockIdx.x;
  const int t = threadIdx.x;
  const int base = bucket_base[b];
  const int tot = bucket_tot[b];
  cnt[t] = 0;
  __syncthreads();
  const int* sp = stageB + base;
  for (int i = t; i < tot; i += 256) atomicAdd(&cnt[sp[i] & 255], 1);
  __syncthreads();
  int v = cnt[t];
  pre[t] = v;
  __syncthreads();
  for (int dlt = 1; dlt < 256; dlt <<= 1) {
    int add = (t >= dlt) ? pre[t - dlt] : 0;
    __syncthreads();
    pre[t] += add;
    __syncthreads();
  }
  const int excl = pre[t] - v;
  cur[t] = excl;
  const int d_self = (b << 8) | t;
  if (d_self < N) offsets[d_self] = base + excl;
  __syncthreads();
  for (int i = t; i < tot; i += 256) {
    int rec = sp[i];
    int dl = rec & 255;
    int s = rec >> 8;
    float e = a_src[s] + a_dst[(b << 8) | dl];
    e = e > 0.f ? e : 0.2f * e;  // leaky_relu(0.2)
    int pos = atomicAdd(&cur[dl], 1);
    int2 r2 = make_int2(s, __float_as_int(e));
    if (pos < CAP_LDS)
      buf[pos] = r2;
    else
      csr_pack[base + pos] = r2;  // safety spill (statistically never)
  }
  __syncthreads();
  const int lim = min(tot, CAP_LDS);
  for (int i = t; i < lim; i += 256) csr_pack[base + i] = buf[i];
}

// ---------------------------------------------------------------------------
// one wave per node, lane = output dim; readlane-broadcast aggregation
// ---------------------------------------------------------------------------
__global__ __launch_bounds__(256) void aggregate_kernel(
    const int* __restrict__ offsets, const int2* __restrict__ csr_pack,
    const float* __restrict__ g, const float* __restrict__ b_gat,
    float* __restrict__ out, int N) {
  const int lane = threadIdx.x & 63;
  const int node = blockIdx.x * 4 + (threadIdx.x >> 6);
  if (node >= N) return;
  const int beg = offsets[node], end = offsets[node + 1];

  float m = -1e30f;
  for (int j = beg + lane; j < end; j += 64)
    m = fmaxf(m, __int_as_float(csr_pack[j].y));
#pragma unroll
  for (int d = 1; d < 64; d <<= 1) m = fmaxf(m, __shfl_xor(m, d, 64));

  float l = 0.f;
  for (int j = beg + lane; j < end; j += 64)
    l += __expf(__int_as_float(csr_pack[j].y) - m);
#pragma unroll
  for (int d = 1; d < 64; d <<= 1) l += __shfl_xor(l, d, 64);
  const float inv_l = 1.f / l;

  float acc0 = 0.f, acc1 = 0.f, acc2 = 0.f, acc3 = 0.f;
  for (int jb = beg; jb < end; jb += 64) {
    int j = jb + lane;
    float p = 0.f;
    int s = 0;
    if (j < end) {
      int2 rec = csr_pack[j];
      p = __expf(__int_as_float(rec.y) - m) * inv_l;
      s = rec.x;
    }
    const int cnt = min(64, end - jb);
    int jj = 0;
    for (; jj + 4 <= cnt; jj += 4) {
      int s0 = __builtin_amdgcn_readlane(s, jj);
      int s1 = __builtin_amdgcn_readlane(s, jj + 1);
      int s2 = __builtin_amdgcn_readlane(s, jj + 2);
      int s3 = __builtin_amdgcn_readlane(s, jj + 3);
      float p0 = readlane_f(p, jj);
      float p1 = readlane_f(p, jj + 1);
      float p2 = readlane_f(p, jj + 2);
      float p3 = readlane_f(p, jj + 3);
      acc0 += p0 * g[((size_t)s0 << 6) + lane];
      acc1 += p1 * g[((size_t)s1 << 6) + lane];
      acc2 += p2 * g[((size_t)s2 << 6) + lane];
      acc3 += p3 * g[((size_t)s3 << 6) + lane];
    }
    for (; jj < cnt; ++jj) {
      int s0 = __builtin_amdgcn_readlane(s, jj);
      float p0 = readlane_f(p, jj);
      acc0 += p0 * g[((size_t)s0 << 6) + lane];
    }
  }
  out[(size_t)node * OUT_DIM + lane] = (acc0 + acc1) + (acc2 + acc3) + b_gat[lane];
}

// ---------------------------------------------------------------------------
extern "C" void kernel_launch(void* const* d_in, const int* in_sizes, int n_in,
                              void* d_out, int out_size, void* d_ws, size_t ws_size,
                              hipStream_t stream) {
  const float* x = (const float*)d_in[0];
  const int* ei = (const int*)d_in[1];
  const float* Wd = (const float*)d_in[2];
  const float* bd = (const float*)d_in[3];
  const float* Wg = (const float*)d_in[4];
  const float* att_src = (const float*)d_in[5];
  const float* att_dst = (const float*)d_in[6];
  const float* bg = (const float*)d_in[7];
  float* out = (float*)d_out;

  const int N = in_sizes[0] / IN_DIM;
  const int E = in_sizes[1] / 2;
  const int T = E + N;
  const int NB = (N + 255) >> 8;                       // 196
  const int nblkP = (T + (1 << SEGSH) - 1) >> SEGSH;   // ~411

  char* ws = (char*)d_ws;
  size_t off = 0;
  auto alloc = [&](size_t bytes) -> void* {
    void* p = ws + off;
    off += (bytes + 15) & ~(size_t)15;
    return p;
  };
  float* h = (float*)alloc((size_t)N * EMBED * 4);
  float* g = (float*)alloc((size_t)N * OUT_DIM * 4);
  float* a_src = (float*)alloc((size_t)N * 4);
  float* a_dst = (float*)alloc((size_t)N * 4);
  int* offsets = (int*)alloc((size_t)(N + 1) * 4);
  int* histT = (int*)alloc((size_t)NBPAD * nblkP * 4);
  int* bucket_base = (int*)alloc((size_t)NBPAD * 4);
  int* bucket_tot = (int*)alloc((size_t)NBPAD * 4);
  int* stageB = (int*)alloc((size_t)T * 4);
  int2* csr_pack = (int2*)alloc((size_t)T * 8);
  unsigned short* Wdh = (unsigned short*)alloc((size_t)EMBED * IN_DIM * 2);
  unsigned short* Wdl = (unsigned short*)alloc((size_t)EMBED * IN_DIM * 2);

  const int WTOT = EMBED * IN_DIM;  // 65536
  hipLaunchKernelGGL(split_w_kernel, dim3(WTOT / 1024), dim3(256), 0, stream,
                     Wd, Wdh, Wdl, WTOT);
  hipLaunchKernelGGL(gemm1_mfma_kernel, dim3((N + 127) / 128, 2), dim3(512), 0,
                     stream, x, Wdh, Wdl, bd, h, N);
  hipLaunchKernelGGL(gemm2_mfma_kernel, dim3((N + 127) / 128), dim3(256), 0,
                     stream, h, Wg, att_src, att_dst, g, a_src, a_dst, N);
  hipLaunchKernelGGL(hist_count_kernel, dim3(nblkP), dim3(256), 0, stream,
                     ei, histT, nblkP, E, N);
  hipLaunchKernelGGL(row_scan_kernel, dim3(NBPAD), dim3(256), 0, stream,
                     histT, bucket_tot, nblkP);
  hipLaunchKernelGGL(base_scan_kernel, dim3(1), dim3(256), 0, stream,
                     bucket_tot, bucket_base, offsets, N, T);
  hipLaunchKernelGGL(bin_kernel, dim3(nblkP), dim3(256), 0, stream,
                     ei, histT, bucket_base, stageB, nblkP, E, N);
  hipLaunchKernelGGL(build_kernel, dim3(NB), dim3(256), 0, stream,
                     stageB, bucket_base, bucket_tot, a_src, a_dst, offsets,
                     csr_pack, N);
  hipLaunchKernelGGL(aggregate_kernel, dim3((N + 3) / 4), dim3(256), 0, stream,
                     offsets, csr_pack, g, bg, out, N);
}

// Round 3
// 315.860 us; speedup vs baseline: 1.1614x; 1.1614x over previous
//
#include <hip/hip_runtime.h>
#include <math.h>

#define IN_DIM 512
#define EMBED 128
#define OUT_DIM 64
#define NBPAD 256      // padded bucket count (actual NB = ceil(N/256) = 196)
#define SEGSH 12       // 4096 edges per bin block
#define CAP_LDS 10240  // build LDS capacity (mean 8430, +19 sigma)

typedef __attribute__((ext_vector_type(8))) short bf16x8;
typedef __attribute__((ext_vector_type(4))) float f32x4;

__device__ __forceinline__ float lrelu(float v, float s) { return v > 0.f ? v : v * s; }

__device__ __forceinline__ float readlane_f(float v, int l) {
  return __int_as_float(__builtin_amdgcn_readlane(__float_as_int(v), l));
}

__device__ __forceinline__ unsigned short f2bf(float f) {
  unsigned int u = __float_as_uint(f);
  u += 0x7fff + ((u >> 16) & 1);  // RTNE
  return (unsigned short)(u >> 16);
}
__device__ __forceinline__ float bf2f(unsigned short h) {
  return __uint_as_float(((unsigned int)h) << 16);
}

// packed f32x2 -> bf16x2 (low half = src0, high half = src1)
__device__ __forceinline__ unsigned int cvt_pk_bf16(float a, float b) {
  unsigned int r;
  asm("v_cvt_pk_bf16_f32 %0, %1, %2" : "=v"(r) : "v"(a), "v"(b));
  return r;
}

// async global->LDS 16B DMA (dest = wave base + lane*16, src per-lane)
__device__ __forceinline__ void gl_lds16(const void* g, void* l) {
  __builtin_amdgcn_global_load_lds(
      (const __attribute__((address_space(1))) unsigned int*)g,
      (__attribute__((address_space(3))) unsigned int*)l, 16, 0, 0);
}

#define LDA 40  // bf16 LDS stride for gemm2 (16B-aligned rows)

// ---------------------------------------------------------------------------
// Prep: split W (fp32) into bf16 hi/lo planes once. 65536 elems -> ~2 us.
// ---------------------------------------------------------------------------
__global__ __launch_bounds__(256) void split_w_kernel(
    const float* __restrict__ W, unsigned short* __restrict__ Wh,
    unsigned short* __restrict__ Wl, int total) {
  int i = (blockIdx.x * 256 + threadIdx.x) * 4;
  if (i >= total) return;
  float4 v = *(const float4*)(W + i);
  unsigned int h0 = cvt_pk_bf16(v.x, v.y);
  unsigned int h1 = cvt_pk_bf16(v.z, v.w);
  float r0 = v.x - __uint_as_float(h0 << 16);
  float r1 = v.y - __uint_as_float(h0 & 0xffff0000u);
  float r2 = v.z - __uint_as_float(h1 << 16);
  float r3 = v.w - __uint_as_float(h1 & 0xffff0000u);
  unsigned int l0 = cvt_pk_bf16(r0, r1);
  unsigned int l1 = cvt_pk_bf16(r2, r3);
  uint2 hh = make_uint2(h0, h1);
  uint2 ll = make_uint2(l0, l1);
  *(uint2*)(Wh + i) = hh;
  *(uint2*)(Wl + i) = ll;
}

// ---------------------------------------------------------------------------
// K1 (MFMA split-bf16): h = leaky_relu(x @ Wd^T + bd, 0.01)
// v4 (m97 structure): 128x128 tile, BK=32, 4 waves, acc 2x8 per wave.
// Staging is pure DMA via global_load_lds (A fp32, B pre-split bf16),
// source-side XOR swizzle -> 2-way (free) LDS reads. fp32->split-bf16
// conversion happens AFTER ds_read, per fragment, via v_cvt_pk_bf16_f32.
// ---------------------------------------------------------------------------
__global__ __launch_bounds__(256) void gemm1_mfma_kernel(
    const float* __restrict__ x, const unsigned short* __restrict__ Wdh,
    const unsigned short* __restrict__ Wdl, const float* __restrict__ bd,
    float* __restrict__ h, int N) {
  // A: 128 rows x 32 k fp32, rows of 128B (8 chunks of 16B)   -> 16 KB
  // B: 128 rows x 32 k bf16 per plane, rows of 64B (4 chunks) ->  8 KB x2
  __shared__ __align__(16) unsigned char Afp[16384];
  __shared__ __align__(16) unsigned char Bhs[8192];
  __shared__ __align__(16) unsigned char Bls[8192];

  const int tid = threadIdx.x;
  const int lane = tid & 63;
  const int wid = tid >> 6;   // 0..3, wave owns rows wid*32..+32
  const int mblk = blockIdx.x * 128;
  const int quad = lane >> 4;
  const int l15 = lane & 15;

  // ---- precompute staging source pointers (per-thread, swizzled) ----
  // A: chunk = i*256 + tid (i=0..3); row = chunk>>3, ch = chunk&7
  // src col chunk = ch ^ (row&7)  (inverse of read-side swizzle; involution)
  const char* asrc[4];
  void* adst[4];
#pragma unroll
  for (int i = 0; i < 4; ++i) {
    int chunk = i * 256 + tid;
    int row = chunk >> 3, ch = chunk & 7;
    int rg = mblk + row;
    if (rg >= N) rg = N - 1;  // clamp: junk rows masked at store
    asrc[i] = (const char*)x + (size_t)rg * (IN_DIM * 4) + ((ch ^ (row & 7)) << 4);
    adst[i] = Afp + chunk * 16;
  }
  // B: chunk = i*256 + tid (i=0..1); row = chunk>>2, ch = chunk&3
  // src chunk = ch ^ ((row>>1)&3)
  const char* bsrcH[2];
  const char* bsrcL[2];
  void* bdstH[2];
  void* bdstL[2];
#pragma unroll
  for (int i = 0; i < 2; ++i) {
    int chunk = i * 256 + tid;
    int row = chunk >> 2, ch = chunk & 3;
    int cs = ch ^ ((row >> 1) & 3);
    size_t srcoff = (size_t)row * (IN_DIM * 2) + (cs << 4);
    bsrcH[i] = (const char*)Wdh + srcoff;
    bsrcL[i] = (const char*)Wdl + srcoff;
    bdstH[i] = Bhs + chunk * 16;
    bdstL[i] = Bls + chunk * 16;
  }

  f32x4 acc[2][8];
#pragma unroll
  for (int i = 0; i < 2; ++i)
#pragma unroll
    for (int j = 0; j < 8; ++j) acc[i][j] = (f32x4){0.f, 0.f, 0.f, 0.f};

  // read-side address components (constant per thread)
  int aoff[2][2];  // [mi][half]
#pragma unroll
  for (int mi = 0; mi < 2; ++mi) {
    int row = wid * 32 + mi * 16 + l15;
    int sw = (row & 7) << 4;
#pragma unroll
    for (int hf = 0; hf < 2; ++hf)
      aoff[mi][hf] = row * 128 + (((quad << 5) | (hf << 4)) ^ sw);
  }
  int boff[8];  // [ni]
#pragma unroll
  for (int ni = 0; ni < 8; ++ni) {
    int row = ni * 16 + l15;
    boff[ni] = row * 64 + ((quad ^ ((row >> 1) & 3)) << 4);
  }

  for (int k0 = 0; k0 < IN_DIM; k0 += 32) {
    __syncthreads();  // previous tile fully consumed
    // ---- stage tile k0 (pure DMA, 8 x 16B per thread) ----
    const size_t ka = (size_t)k0 * 4;  // byte advance in x
    const size_t kb = (size_t)k0 * 2;  // byte advance in W planes
#pragma unroll
    for (int i = 0; i < 4; ++i) gl_lds16(asrc[i] + ka, adst[i]);
#pragma unroll
    for (int i = 0; i < 2; ++i) {
      gl_lds16(bsrcH[i] + kb, bdstH[i]);
      gl_lds16(bsrcL[i] + kb, bdstL[i]);
    }
    __syncthreads();  // vmcnt drain + visibility

    // ---- A fragments: ds_read fp32, convert to split bf16 ----
    bf16x8 AH[2], AL[2];
#pragma unroll
    for (int mi = 0; mi < 2; ++mi) {
      float4 f0 = *(const float4*)(Afp + aoff[mi][0]);
      float4 f1 = *(const float4*)(Afp + aoff[mi][1]);
      float av[8] = {f0.x, f0.y, f0.z, f0.w, f1.x, f1.y, f1.z, f1.w};
      union { unsigned int u[4]; bf16x8 v; } H, L;
#pragma unroll
      for (int i = 0; i < 4; ++i) {
        unsigned int hp = cvt_pk_bf16(av[2 * i], av[2 * i + 1]);
        float q0 = av[2 * i] - __uint_as_float(hp << 16);
        float q1 = av[2 * i + 1] - __uint_as_float(hp & 0xffff0000u);
        H.u[i] = hp;
        L.u[i] = cvt_pk_bf16(q0, q1);
      }
      AH[mi] = H.v;
      AL[mi] = L.v;
    }

    // ---- B fragments in two halves (register pressure) + MFMA ----
#pragma unroll
    for (int hf = 0; hf < 2; ++hf) {
      bf16x8 BH[4], BL[4];
#pragma unroll
      for (int j = 0; j < 4; ++j) {
        BH[j] = *(const bf16x8*)(Bhs + boff[hf * 4 + j]);
        BL[j] = *(const bf16x8*)(Bls + boff[hf * 4 + j]);
      }
#pragma unroll
      for (int mi = 0; mi < 2; ++mi)
#pragma unroll
        for (int j = 0; j < 4; ++j) {
          int ni = hf * 4 + j;
          acc[mi][ni] = __builtin_amdgcn_mfma_f32_16x16x32_bf16(AH[mi], BH[j], acc[mi][ni], 0, 0, 0);
          acc[mi][ni] = __builtin_amdgcn_mfma_f32_16x16x32_bf16(AL[mi], BH[j], acc[mi][ni], 0, 0, 0);
          acc[mi][ni] = __builtin_amdgcn_mfma_f32_16x16x32_bf16(AH[mi], BL[j], acc[mi][ni], 0, 0, 0);
        }
    }
  }

  // ---- epilogue: bias + leaky_relu, masked store ----
#pragma unroll
  for (int mi = 0; mi < 2; ++mi)
#pragma unroll
    for (int ni = 0; ni < 8; ++ni) {
      int n = ni * 16 + l15;
      float b = bd[n];
#pragma unroll
      for (int r = 0; r < 4; ++r) {
        int m = mblk + wid * 32 + mi * 16 + quad * 4 + r;
        if (m < N) h[(size_t)m * EMBED + n] = lrelu(acc[mi][ni][r] + b, 0.01f);
      }
    }
}

// ---------------------------------------------------------------------------
// K2 (MFMA split-bf16): g = h @ Wg^T, fused att-dot epilogue.
// (round-0 structure, unchanged)
// ---------------------------------------------------------------------------
__global__ __launch_bounds__(256) void gemm2_mfma_kernel(
    const float* __restrict__ h, const float* __restrict__ Wg,
    const float* __restrict__ att_src, const float* __restrict__ att_dst,
    float* __restrict__ g, float* __restrict__ a_src, float* __restrict__ a_dst,
    int N) {
  __shared__ __align__(16) unsigned short Ah[128][LDA];
  __shared__ __align__(16) unsigned short Al[128][LDA];
  __shared__ __align__(16) unsigned short Bh[64][LDA];
  __shared__ __align__(16) unsigned short Bl[64][LDA];

  const int tid = threadIdx.x;
  const int lane = tid & 63;
  const int wid = tid >> 6;
  const int wr = wid >> 1, wc = wid & 1;
  const int mblk = blockIdx.x * 128;
  const int quad = lane >> 4;
  const int l15 = lane & 15;

  const int arow = tid >> 1, acb = (tid & 1) * 16;
  const int brow = tid >> 2, bcb = (tid & 3) * 8;
  const bool avalid = (mblk + arow) < N;
  const float* aptr = h + (size_t)(mblk + arow) * EMBED + acb;
  const float* bptr = Wg + (size_t)brow * EMBED + bcb;

  f32x4 acc[4][2];
#pragma unroll
  for (int i = 0; i < 4; ++i)
#pragma unroll
    for (int j = 0; j < 2; ++j) acc[i][j] = (f32x4){0.f, 0.f, 0.f, 0.f};

  float4 t0, t1, t2, t3, u0, u1;
  auto do_load = [&](int k0) {
    if (avalid) {
      t0 = *(const float4*)(aptr + k0);
      t1 = *(const float4*)(aptr + k0 + 4);
      t2 = *(const float4*)(aptr + k0 + 8);
      t3 = *(const float4*)(aptr + k0 + 12);
    } else {
      t0 = t1 = t2 = t3 = make_float4(0.f, 0.f, 0.f, 0.f);
    }
    u0 = *(const float4*)(bptr + k0);
    u1 = *(const float4*)(bptr + k0 + 4);
  };
  do_load(0);

  for (int k0 = 0; k0 < EMBED; k0 += 32) {
    float av[16] = {t0.x, t0.y, t0.z, t0.w, t1.x, t1.y, t1.z, t1.w,
                    t2.x, t2.y, t2.z, t2.w, t3.x, t3.y, t3.z, t3.w};
    union { unsigned short us[16]; uint4 v[2]; } AH, AL;
#pragma unroll
    for (int i = 0; i < 16; ++i) {
      unsigned short hi = f2bf(av[i]);
      AH.us[i] = hi;
      AL.us[i] = f2bf(av[i] - bf2f(hi));
    }
    float bv[8] = {u0.x, u0.y, u0.z, u0.w, u1.x, u1.y, u1.z, u1.w};
    union { unsigned short us[8]; uint4 v; } BH, BL;
#pragma unroll
    for (int i = 0; i < 8; ++i) {
      unsigned short hi = f2bf(bv[i]);
      BH.us[i] = hi;
      BL.us[i] = f2bf(bv[i] - bf2f(hi));
    }

    __syncthreads();
    *(uint4*)&Ah[arow][acb] = AH.v[0];
    *(uint4*)&Ah[arow][acb + 8] = AH.v[1];
    *(uint4*)&Al[arow][acb] = AL.v[0];
    *(uint4*)&Al[arow][acb + 8] = AL.v[1];
    *(uint4*)&Bh[brow][bcb] = BH.v;
    *(uint4*)&Bl[brow][bcb] = BL.v;
    __syncthreads();

    if (k0 + 32 < EMBED) do_load(k0 + 32);

    bf16x8 ah[4], al[4], bh[2], bl[2];
#pragma unroll
    for (int mi = 0; mi < 4; ++mi) {
      int r = wr * 64 + mi * 16 + l15;
      ah[mi] = *(const bf16x8*)&Ah[r][quad * 8];
      al[mi] = *(const bf16x8*)&Al[r][quad * 8];
    }
#pragma unroll
    for (int ni = 0; ni < 2; ++ni) {
      int r = wc * 32 + ni * 16 + l15;
      bh[ni] = *(const bf16x8*)&Bh[r][quad * 8];
      bl[ni] = *(const bf16x8*)&Bl[r][quad * 8];
    }
#pragma unroll
    for (int mi = 0; mi < 4; ++mi)
#pragma unroll
      for (int ni = 0; ni < 2; ++ni) {
        acc[mi][ni] = __builtin_amdgcn_mfma_f32_16x16x32_bf16(ah[mi], bh[ni], acc[mi][ni], 0, 0, 0);
        acc[mi][ni] = __builtin_amdgcn_mfma_f32_16x16x32_bf16(al[mi], bh[ni], acc[mi][ni], 0, 0, 0);
        acc[mi][ni] = __builtin_amdgcn_mfma_f32_16x16x32_bf16(ah[mi], bl[ni], acc[mi][ni], 0, 0, 0);
      }
  }

  float as_[2], ad_[2];
#pragma unroll
  for (int ni = 0; ni < 2; ++ni) {
    int n = wc * 32 + ni * 16 + l15;
    as_[ni] = att_src[n];
    ad_[ni] = att_dst[n];
  }
#pragma unroll
  for (int mi = 0; mi < 4; ++mi) {
#pragma unroll
    for (int r = 0; r < 4; ++r) {
      int m = mblk + wr * 64 + mi * 16 + quad * 4 + r;
      float ps = acc[mi][0][r] * as_[0] + acc[mi][1][r] * as_[1];
      float pd = acc[mi][0][r] * ad_[0] + acc[mi][1][r] * ad_[1];
#pragma unroll
      for (int d = 1; d < 16; d <<= 1) {
        ps += __shfl_xor(ps, d, 64);
        pd += __shfl_xor(pd, d, 64);
      }
      if (m < N) {
#pragma unroll
        for (int ni = 0; ni < 2; ++ni) {
          int n = wc * 32 + ni * 16 + l15;
          g[(size_t)m * OUT_DIM + n] = acc[mi][ni][r];
        }
        if (l15 == 0 && wc == 0) {
          a_src[m] = ps;
          a_dst[m] = pd;
        }
      }
    }
  }
  __syncthreads();
#pragma unroll
  for (int mi = 0; mi < 4; ++mi) {
#pragma unroll
    for (int r = 0; r < 4; ++r) {
      int m = mblk + wr * 64 + mi * 16 + quad * 4 + r;
      float ps = acc[mi][0][r] * as_[0] + acc[mi][1][r] * as_[1];
      float pd = acc[mi][0][r] * ad_[0] + acc[mi][1][r] * ad_[1];
#pragma unroll
      for (int d = 1; d < 16; d <<= 1) {
        ps += __shfl_xor(ps, d, 64);
        pd += __shfl_xor(pd, d, 64);
      }
      if (m < N && l15 == 0 && wc == 1) {
        atomicAdd(&a_src[m], ps);
        atomicAdd(&a_dst[m], pd);
      }
    }
  }
}

// ---------------------------------------------------------------------------
// Edge phase (deterministic software write-combining bin, parallel alloc)
// ---------------------------------------------------------------------------
__global__ __launch_bounds__(256) void hist_count_kernel(
    const int* __restrict__ ei, int* __restrict__ histT, int nblkP, int E,
    int N) {
  __shared__ int cnt[NBPAD];
  const int t = threadIdx.x;
  cnt[t] = 0;
  __syncthreads();
  const int T = E + N;
  const int base = blockIdx.x << SEGSH;
#pragma unroll
  for (int q = 0; q < (1 << SEGSH) / 256; ++q) {
    int i = base + q * 256 + t;
    if (i < T) {
      int d = (i < E) ? ei[E + i] : (i - E);
      atomicAdd(&cnt[d >> 8], 1);
    }
  }
  __syncthreads();
  histT[(size_t)t * nblkP + blockIdx.x] = cnt[t];
}

__global__ __launch_bounds__(256) void row_scan_kernel(
    int* __restrict__ histT, int* __restrict__ bucket_tot, int nblkP) {
  __shared__ int sc[256];
  const int t = threadIdx.x;
  int* row = histT + (size_t)blockIdx.x * nblkP;
  const int per = (nblkP + 255) / 256;
  int loc[8];
  int sum = 0;
#pragma unroll 4
  for (int j = 0; j < per; ++j) {
    int idx = t * per + j;
    int v = (idx < nblkP) ? row[idx] : 0;
    loc[j] = sum;
    sum += v;
  }
  sc[t] = sum;
  __syncthreads();
  for (int dlt = 1; dlt < 256; dlt <<= 1) {
    int add = (t >= dlt) ? sc[t - dlt] : 0;
    __syncthreads();
    sc[t] += add;
    __syncthreads();
  }
  const int off = sc[t] - sum;
#pragma unroll 4
  for (int j = 0; j < per; ++j) {
    int idx = t * per + j;
    if (idx < nblkP) row[idx] = off + loc[j];
  }
  if (t == 255) bucket_tot[blockIdx.x] = sc[255];
}

__global__ __launch_bounds__(256) void base_scan_kernel(
    const int* __restrict__ bucket_tot, int* __restrict__ bucket_base,
    int* __restrict__ offsets, int N, int T) {
  __shared__ int sc[256];
  const int t = threadIdx.x;
  int v = bucket_tot[t];
  sc[t] = v;
  __syncthreads();
  for (int dlt = 1; dlt < 256; dlt <<= 1) {
    int add = (t >= dlt) ? sc[t - dlt] : 0;
    __syncthreads();
    sc[t] += add;
    __syncthreads();
  }
  bucket_base[t] = sc[t] - v;
  if (t == 0) offsets[N] = T;
}

__global__ __launch_bounds__(256) void bin_kernel(
    const int* __restrict__ ei, const int* __restrict__ histT,
    const int* __restrict__ bucket_base, int* __restrict__ stageB, int nblkP,
    int E, int N) {
  __shared__ int cnt[NBPAD];
  __shared__ int basev[NBPAD];
  const int t = threadIdx.x;
  cnt[t] = 0;
  basev[t] = bucket_base[t] + histT[(size_t)t * nblkP + blockIdx.x];
  __syncthreads();
  const int T = E + N;
  const int base = blockIdx.x << SEGSH;
#pragma unroll
  for (int q = 0; q < (1 << SEGSH) / 256; ++q) {
    int i = base + q * 256 + t;
    if (i < T) {
      int s, d;
      if (i < E) {
        s = ei[i];
        d = ei[E + i];
      } else {
        s = d = i - E;
      }
      int b = d >> 8;
      int r = atomicAdd(&cnt[b], 1);
      stageB[basev[b] + r] = (s << 8) | (d & 255);
    }
  }
}

__global__ __launch_bounds__(256) void build_kernel(
    const int* __restrict__ stageB, const int* __restrict__ bucket_base,
    const int* __restrict__ bucket_tot, const float* __restrict__ a_src,
    const float* __restrict__ a_dst, int* __restrict__ offsets,
    int2* __restrict__ csr_pack, int N) {
  __shared__ int cnt[256];
  __shared__ int pre[256];
  __shared__ int cur[256];
  __shared__ int2 buf[CAP_LDS];
  const int b = blockIdx.x;
  const int t = threadIdx.x;
  const int base = bucket_base[b];
  const int tot = bucket_tot[b];
  cnt[t] = 0;
  __syncthreads();
  const int* sp = stageB + base;
  for (int i = t; i < tot; i += 256) atomicAdd(&cnt[sp[i] & 255], 1);
  __syncthreads();
  int v = cnt[t];
  pre[t] = v;
  __syncthreads();
  for (int dlt = 1; dlt < 256; dlt <<= 1) {
    int add = (t >= dlt) ? pre[t - dlt] : 0;
    __syncthreads();
    pre[t] += add;
    __syncthreads();
  }
  const int excl = pre[t] - v;
  cur[t] = excl;
  const int d_self = (b << 8) | t;
  if (d_self < N) offsets[d_self] = base + excl;
  __syncthreads();
  for (int i = t; i < tot; i += 256) {
    int rec = sp[i];
    int dl = rec & 255;
    int s = rec >> 8;
    float e = a_src[s] + a_dst[(b << 8) | dl];
    e = e > 0.f ? e : 0.2f * e;  // leaky_relu(0.2)
    int pos = atomicAdd(&cur[dl], 1);
    int2 r2 = make_int2(s, __float_as_int(e));
    if (pos < CAP_LDS)
      buf[pos] = r2;
    else
      csr_pack[base + pos] = r2;  // safety spill (statistically never)
  }
  __syncthreads();
  const int lim = min(tot, CAP_LDS);
  for (int i = t; i < lim; i += 256) csr_pack[base + i] = buf[i];
}

// ---------------------------------------------------------------------------
// one wave per node, lane = output dim; readlane-broadcast aggregation
// ---------------------------------------------------------------------------
__global__ __launch_bounds__(256) void aggregate_kernel(
    const int* __restrict__ offsets, const int2* __restrict__ csr_pack,
    const float* __restrict__ g, const float* __restrict__ b_gat,
    float* __restrict__ out, int N) {
  const int lane = threadIdx.x & 63;
  const int node = blockIdx.x * 4 + (threadIdx.x >> 6);
  if (node >= N) return;
  const int beg = offsets[node], end = offsets[node + 1];

  float m = -1e30f;
  for (int j = beg + lane; j < end; j += 64)
    m = fmaxf(m, __int_as_float(csr_pack[j].y));
#pragma unroll
  for (int d = 1; d < 64; d <<= 1) m = fmaxf(m, __shfl_xor(m, d, 64));

  float l = 0.f;
  for (int j = beg + lane; j < end; j += 64)
    l += __expf(__int_as_float(csr_pack[j].y) - m);
#pragma unroll
  for (int d = 1; d < 64; d <<= 1) l += __shfl_xor(l, d, 64);
  const float inv_l = 1.f / l;

  float acc0 = 0.f, acc1 = 0.f, acc2 = 0.f, acc3 = 0.f;
  for (int jb = beg; jb < end; jb += 64) {
    int j = jb + lane;
    float p = 0.f;
    int s = 0;
    if (j < end) {
      int2 rec = csr_pack[j];
      p = __expf(__int_as_float(rec.y) - m) * inv_l;
      s = rec.x;
    }
    const int cnt = min(64, end - jb);
    int jj = 0;
    for (; jj + 4 <= cnt; jj += 4) {
      int s0 = __builtin_amdgcn_readlane(s, jj);
      int s1 = __builtin_amdgcn_readlane(s, jj + 1);
      int s2 = __builtin_amdgcn_readlane(s, jj + 2);
      int s3 = __builtin_amdgcn_readlane(s, jj + 3);
      float p0 = readlane_f(p, jj);
      float p1 = readlane_f(p, jj + 1);
      float p2 = readlane_f(p, jj + 2);
      float p3 = readlane_f(p, jj + 3);
      acc0 += p0 * g[((size_t)s0 << 6) + lane];
      acc1 += p1 * g[((size_t)s1 << 6) + lane];
      acc2 += p2 * g[((size_t)s2 << 6) + lane];
      acc3 += p3 * g[((size_t)s3 << 6) + lane];
    }
    for (; jj < cnt; ++jj) {
      int s0 = __builtin_amdgcn_readlane(s, jj);
      float p0 = readlane_f(p, jj);
      acc0 += p0 * g[((size_t)s0 << 6) + lane];
    }
  }
  out[(size_t)node * OUT_DIM + lane] = (acc0 + acc1) + (acc2 + acc3) + b_gat[lane];
}

// ---------------------------------------------------------------------------
extern "C" void kernel_launch(void* const* d_in, const int* in_sizes, int n_in,
                              void* d_out, int out_size, void* d_ws, size_t ws_size,
                              hipStream_t stream) {
  const float* x = (const float*)d_in[0];
  const int* ei = (const int*)d_in[1];
  const float* Wd = (const float*)d_in[2];
  const float* bd = (const float*)d_in[3];
  const float* Wg = (const float*)d_in[4];
  const float* att_src = (const float*)d_in[5];
  const float* att_dst = (const float*)d_in[6];
  const float* bg = (const float*)d_in[7];
  float* out = (float*)d_out;

  const int N = in_sizes[0] / IN_DIM;
  const int E = in_sizes[1] / 2;
  const int T = E + N;
  const int NB = (N + 255) >> 8;                       // 196
  const int nblkP = (T + (1 << SEGSH) - 1) >> SEGSH;   // ~411

  char* ws = (char*)d_ws;
  size_t off = 0;
  auto alloc = [&](size_t bytes) -> void* {
    void* p = ws + off;
    off += (bytes + 15) & ~(size_t)15;
    return p;
  };
  float* h = (float*)alloc((size_t)N * EMBED * 4);
  float* g = (float*)alloc((size_t)N * OUT_DIM * 4);
  float* a_src = (float*)alloc((size_t)N * 4);
  float* a_dst = (float*)alloc((size_t)N * 4);
  int* offsets = (int*)alloc((size_t)(N + 1) * 4);
  int* histT = (int*)alloc((size_t)NBPAD * nblkP * 4);
  int* bucket_base = (int*)alloc((size_t)NBPAD * 4);
  int* bucket_tot = (int*)alloc((size_t)NBPAD * 4);
  int* stageB = (int*)alloc((size_t)T * 4);
  int2* csr_pack = (int2*)alloc((size_t)T * 8);
  unsigned short* Wdh = (unsigned short*)alloc((size_t)EMBED * IN_DIM * 2);
  unsigned short* Wdl = (unsigned short*)alloc((size_t)EMBED * IN_DIM * 2);

  const int WTOT = EMBED * IN_DIM;  // 65536
  hipLaunchKernelGGL(split_w_kernel, dim3(WTOT / 1024), dim3(256), 0, stream,
                     Wd, Wdh, Wdl, WTOT);
  hipLaunchKernelGGL(gemm1_mfma_kernel, dim3((N + 127) / 128), dim3(256), 0,
                     stream, x, Wdh, Wdl, bd, h, N);
  hipLaunchKernelGGL(gemm2_mfma_kernel, dim3((N + 127) / 128), dim3(256), 0,
                     stream, h, Wg, att_src, att_dst, g, a_src, a_dst, N);
  hipLaunchKernelGGL(hist_count_kernel, dim3(nblkP), dim3(256), 0, stream,
                     ei, histT, nblkP, E, N);
  hipLaunchKernelGGL(row_scan_kernel, dim3(NBPAD), dim3(256), 0, stream,
                     histT, bucket_tot, nblkP);
  hipLaunchKernelGGL(base_scan_kernel, dim3(1), dim3(256), 0, stream,
                     bucket_tot, bucket_base, offsets, N, T);
  hipLaunchKernelGGL(bin_kernel, dim3(nblkP), dim3(256), 0, stream,
                     ei, histT, bucket_base, stageB, nblkP, E, N);
  hipLaunchKernelGGL(build_kernel, dim3(NB), dim3(256), 0, stream,
                     stageB, bucket_base, bucket_tot, a_src, a_dst, offsets,
                     csr_pack, N);
  hipLaunchKernelGGL(aggregate_kernel, dim3((N + 3) / 4), dim3(256), 0, stream,
                     offsets, csr_pack, g, bg, out, N);
}